// Round 19
// baseline (271.409 us; speedup 1.0000x reference)
//
#include <hip/hip_runtime.h>

// s_gcn R19: wave-autonomous, ZERO-barrier kernel.
// Diagnosis: R13-R18 all null/negative inside the barrier-synced 8-wave
// structure; every pipe <25% busy, ~35us work in 121us wall -> the 17
// whole-block barrier convergences are the wall.
// Structure: 256-thr blocks, 4 waves; each wave owns private LDS slices
//   xs (x tile f32 [64ci][25v] packed) and hs (H tile bf16 [64c][32v^swz])
// and processes 4 t's end-to-end. Same-wave DS ops are in-order -> no
// __syncthreads at all. W/A/bias2 fragments from L2-hot prepped buffers.
// v>=25 garbage killed by zeroed abuf rows; xs tail zeroed (finite-junk rule).

typedef short short8 __attribute__((ext_vector_type(8)));
typedef float floatx4 __attribute__((ext_vector_type(4)));
typedef unsigned int uintx4 __attribute__((ext_vector_type(4)));

#define K_NUM 3
#define C_IN  64
#define C_OUT 64
#define T_DIM 2048
#define V_DIM 25
#define N_DIM 16
#define XROW  (T_DIM * V_DIM)   // 51200

#define TW    4                  // t per wave
#define TWIN  16                 // t per block (4 waves)

#define WBUF_ELEMS (3*4*2*64*8)  // [k][ni][ks][lane][j] u16 = 12288
#define ABUF_OFF   (WBUF_ELEMS*2)            // 24576 B
#define ABUF_ELEMS (3*2*64*8)                // [k][nt][lane][j] u16 = 3072
#define B2_OFF     (ABUF_OFF + ABUF_ELEMS*2) // 30720 B
#define B2_ELEMS   (4*2*64*4)                // [mt][nt][lane][r] f32

__device__ __forceinline__ unsigned short bf16_rne(float f) {
    unsigned int u = __builtin_bit_cast(unsigned int, f);
    unsigned int r = (u + 0x7FFFu + ((u >> 16) & 1u)) >> 16;
    return (unsigned short)r;
}
// {bf16(fx) lo16, bf16(fy) hi16}, round-half-up
__device__ __forceinline__ unsigned int pack_rh(float fx, float fy) {
    unsigned int ux = __builtin_bit_cast(unsigned int, fx);
    unsigned int uy = __builtin_bit_cast(unsigned int, fy);
    return ((ux + 0x8000u) >> 16) | ((uy + 0x8000u) & 0xFFFF0000u);
}

__global__ void sgcn_prep(const float* __restrict__ W, const float* __restrict__ A,
                          const float* __restrict__ b,
                          unsigned short* __restrict__ wbuf,
                          unsigned short* __restrict__ abuf,
                          float* __restrict__ b2buf) {
    int idx = blockIdx.x * 256 + threadIdx.x;
    if (idx < WBUF_ELEMS) {   // B-op stage-1: n=c (lane&15), k=ci
        int j = idx & 7, lane = (idx >> 3) & 63, ks = (idx >> 9) & 1;
        int ni = (idx >> 10) & 3, k = idx >> 12;
        int o  = k * 64 + ni * 16 + (lane & 15);
        int ci = ks * 32 + ((lane >> 4) & 3) * 8 + j;
        wbuf[idx] = bf16_rne(W[o * C_IN + ci]);
    }
    if (idx < ABUF_ELEMS) {   // B-op stage-2: n=w, k=v (K=32; v>=25 zeroed)
        int j = idx & 7, lane = (idx >> 3) & 63, nt = (idx >> 9) & 1, k = idx >> 10;
        int w = nt * 16 + (lane & 15);
        int v = ((lane >> 4) & 3) * 8 + j;
        abuf[idx] = (v < V_DIM && w < V_DIM) ? bf16_rne(A[(k * V_DIM + v) * V_DIM + w])
                                             : (unsigned short)0;
    }
    if (idx < B2_ELEMS) {     // stage-2 C init: c=(lane>>4)*4+r (+mt*16), w=lane&15 (+nt*16)
        int r = idx & 3, lane = (idx >> 2) & 63, nt = (idx >> 8) & 1, mt = idx >> 9;
        int c = mt * 16 + ((lane >> 4) & 3) * 4 + r;
        int w = nt * 16 + (lane & 15);
        float val = 0.f;
        if (w < V_DIM) {
            for (int k = 0; k < K_NUM; ++k) {
                float cs = 0.f;
                for (int v = 0; v < V_DIM; ++v) cs += A[(k * V_DIM + v) * V_DIM + w];
                val += b[k * C_OUT + c] * cs;
            }
        }
        b2buf[idx] = val;
    }
}

__global__ __launch_bounds__(256)
void sgcn_main(const float* __restrict__ x,
               const unsigned short* __restrict__ wbuf,
               const unsigned short* __restrict__ abuf,
               const float* __restrict__ b2buf,
               float* __restrict__ out) {
    // wave-private slices (no cross-wave sharing, no barriers)
    __shared__ __align__(16) float          xs[4][1664];     // [ci*25+v] + 64 zero tail, 6.5KB each
    __shared__ __align__(16) unsigned short hs[4][64 * 32];  // [c][v^swz], 4KB each

    const int tid  = threadIdx.x;
    const int lane = tid & 63;
    const int wid  = tid >> 6;
    const int nb   = blockIdx.x >> 7;
    const int t0   = (blockIdx.x & 127) * TWIN + wid * TW;

    float* xw = xs[wid];
    unsigned short* hw = hs[wid];

    const short8*  wbuf8 = (const short8*)wbuf;
    const short8*  abuf8 = (const short8*)abuf;
    const floatx4* b2b4  = (const floatx4*)b2buf;
    const float*   xbase = x + (size_t)nb * C_IN * XROW;

    xw[1600 + lane] = 0.f;   // finite tail for over-reads at v in [25,32)

    const int kg = (lane >> 4) & 3;   // k-group within wave
    const int ln = lane & 15;

    // stage x tile for time t into xw (packed [ci][25] f32): 25 coalesced-ish
    // load/store pairs; ds in-order vs earlier reads of the same slice.
    auto STAGE = [&](int t) {
        #pragma unroll
        for (int i = 0; i < 25; ++i) {
            int u  = i * 64 + lane;      // < 1600
            int ci = u / 25, v = u - ci * 25;
            xw[u] = xbase[(size_t)ci * XROW + t * V_DIM + v];
        }
    };

    STAGE(t0);

    #pragma unroll 1
    for (int j = 0; j < TW; ++j) {
        const int t = t0 + j;

        // ---- stage-1 A-frags: m=v (mi*16+ln), k=ci (ks*32+kg*8+jj) ----
        short8 xfr[2][2];
        #pragma unroll
        for (int mi = 0; mi < 2; ++mi) {
            const int v = mi * 16 + ln;   // 0..31; v>=25 reads tail/junk (finite, killed by abuf zeros)
            #pragma unroll
            for (int ks = 0; ks < 2; ++ks) {
                const int cib = ks * 32 + kg * 8;
                float f0 = xw[(cib + 0) * 25 + v], f1 = xw[(cib + 1) * 25 + v];
                float f2 = xw[(cib + 2) * 25 + v], f3 = xw[(cib + 3) * 25 + v];
                float f4 = xw[(cib + 4) * 25 + v], f5 = xw[(cib + 5) * 25 + v];
                float f6 = xw[(cib + 6) * 25 + v], f7 = xw[(cib + 7) * 25 + v];
                uintx4 p;
                p[0] = pack_rh(f0, f1); p[1] = pack_rh(f2, f3);
                p[2] = pack_rh(f4, f5); p[3] = pack_rh(f6, f7);
                xfr[mi][ks] = __builtin_bit_cast(short8, p);
            }
        }

        if (j + 1 < TW) STAGE(t + 1);   // slice free after xfr reads (ds in-order)

        // ---- acc2 init from bias2 table (L2-hot) ----
        floatx4 acc2[4][2];
        #pragma unroll
        for (int mt = 0; mt < 4; ++mt)
            #pragma unroll
            for (int nt = 0; nt < 2; ++nt)
                acc2[mt][nt] = b2b4[(mt * 2 + nt) * 64 + lane];

        // ---- per-k: stage-1 -> hs -> stage-2 partial (hs reused, ds in-order) ----
        #pragma unroll
        for (int k = 0; k < K_NUM; ++k) {
            floatx4 acc1[2][4];
            #pragma unroll
            for (int mi = 0; mi < 2; ++mi)
                #pragma unroll
                for (int ni = 0; ni < 4; ++ni)
                    acc1[mi][ni] = floatx4{0.f, 0.f, 0.f, 0.f};

            #pragma unroll
            for (int ks = 0; ks < 2; ++ks)
                #pragma unroll
                for (int ni = 0; ni < 4; ++ni) {
                    short8 wf = wbuf8[((k * 4 + ni) * 2 + ks) * 64 + lane];
                    #pragma unroll
                    for (int mi = 0; mi < 2; ++mi)
                        acc1[mi][ni] = __builtin_amdgcn_mfma_f32_16x16x32_bf16(
                            xfr[mi][ks], wf, acc1[mi][ni], 0, 0, 0);
                }

            // hs write: C[m=v][n=c]: c = ni*16+ln, v = mi*16+kg*4+r -> b64
            #pragma unroll
            for (int mi = 0; mi < 2; ++mi) {
                const int vb = mi * 16 + kg * 4;
                #pragma unroll
                for (int ni = 0; ni < 4; ++ni) {
                    const int c   = ni * 16 + ln;
                    const int swv = vb ^ (((c >> 2) & 3) << 3);
                    unsigned long long lo = pack_rh(acc1[mi][ni][0], acc1[mi][ni][1]);
                    unsigned long long hi = pack_rh(acc1[mi][ni][2], acc1[mi][ni][3]);
                    ((unsigned long long*)hw)[(c * 32 + swv) >> 2] = lo | (hi << 32);
                }
            }

            // stage-2: A-op m=c, k=v from hs; B-op from abuf
            short8 ha[4];
            #pragma unroll
            for (int mt = 0; mt < 4; ++mt) {
                const int c_a = mt * 16 + ln;
                const int blk = kg ^ ((c_a >> 2) & 3);
                ha[mt] = *(const short8*)&((const unsigned int*)hw)[c_a * 16 + blk * 4];
            }
            #pragma unroll
            for (int nt = 0; nt < 2; ++nt) {
                short8 af = abuf8[(k * 2 + nt) * 64 + lane];
                #pragma unroll
                for (int mt = 0; mt < 4; ++mt)
                    acc2[mt][nt] = __builtin_amdgcn_mfma_f32_16x16x32_bf16(
                        ha[mt], af, acc2[mt][nt], 0, 0, 0);
            }
        }

        // ---- stores: C[m=c][n=w]: c = mt*16+kg*4+r, w = nt*16+ln ----
        #pragma unroll
        for (int mt = 0; mt < 4; ++mt) {
            const int c0 = mt * 16 + kg * 4;
            #pragma unroll
            for (int r = 0; r < 4; ++r) {
                float* ob = out + ((size_t)(nb * C_OUT + c0 + r) * T_DIM + t) * V_DIM;
                ob[ln] = acc2[mt][0][r];                    // w = 0..15
                if (ln < 9) ob[16 + ln] = acc2[mt][1][r];   // w = 16..24
            }
        }
    }
}

extern "C" void kernel_launch(void* const* d_in, const int* in_sizes, int n_in,
                              void* d_out, int out_size, void* d_ws, size_t ws_size,
                              hipStream_t stream) {
    const float* x = (const float*)d_in[0];
    const float* A = (const float*)d_in[1];
    const float* W = (const float*)d_in[2];
    const float* b = (const float*)d_in[3];
    float* out = (float*)d_out;

    unsigned short* wbuf = (unsigned short*)d_ws;
    unsigned short* abuf = (unsigned short*)((char*)d_ws + ABUF_OFF);
    float* b2buf = (float*)((char*)d_ws + B2_OFF);

    sgcn_prep<<<(WBUF_ELEMS + 255) / 256, 256, 0, stream>>>(W, A, b, wbuf, abuf, b2buf);

    dim3 grid(N_DIM * (T_DIM / TWIN));   // 16 * 128 = 2048 blocks x 256 threads
    sgcn_main<<<grid, 256, 0, stream>>>(x, wbuf, abuf, b2buf, out);
}

// Round 20
// 121.480 us; speedup vs baseline: 2.2342x; 2.2342x over previous
//
#include <hip/hip_runtime.h>

// s_gcn FINAL (= R16, best: 121.0us, absmax 0.125).
// Plain-bf16 MFMA, two fused GEMM stages, single-barrier pipelined dbuf,
// b128 staging writes, round-half-up bf16 pair-pack, depth-1 x prefetch.
// Session: 1450us (R1 naive) -> 121us via: coalesced writes (R2), LDS-pipe
// vectorization (R4), bf16-split MFMA (R6), bias-fold + spill-control (R8),
// plain-bf16 + swizzles (R12), single-barrier pipeline (R13), pack_rh (R16).
// R13-R19 structural probes (depth-2 prefetch, store-transpose, zero-barrier,
// occupancy-grid, cvt_pk asm) all null/negative -> this is the floor of this
// design; remaining headroom needs in-register H redistribution whose
// shuffle cost exceeds the LDS round-trip it removes.

typedef short short8 __attribute__((ext_vector_type(8)));
typedef float floatx4 __attribute__((ext_vector_type(4)));
typedef unsigned int uintx4 __attribute__((ext_vector_type(4)));

#define K_NUM 3
#define C_IN  64
#define C_OUT 64
#define T_DIM 2048
#define V_DIM 25
#define N_DIM 16

#define TT    2
#define NSUB  16
#define TWIN  32
#define XROW  51200   // T_DIM*V_DIM

#define WBUF_ELEMS (12*2*64*8)
#define ABUF_OFF   (WBUF_ELEMS*2)
#define ABUF_ELEMS (3*2*64*8)
#define B2_OFF     (ABUF_OFF + ABUF_ELEMS*2)
#define B2_ELEMS   (4*2*64*4)

__device__ __forceinline__ unsigned short bf16_rne(float f) {
    unsigned int u = __builtin_bit_cast(unsigned int, f);
    unsigned int r = (u + 0x7FFFu + ((u >> 16) & 1u)) >> 16;
    return (unsigned short)r;
}
// {bf16(fx) in lo16, bf16(fy) in hi16}, round-half-up (5 VALU ops)
__device__ __forceinline__ unsigned int pack_rh(float fx, float fy) {
    unsigned int ux = __builtin_bit_cast(unsigned int, fx);
    unsigned int uy = __builtin_bit_cast(unsigned int, fy);
    return ((ux + 0x8000u) >> 16) | ((uy + 0x8000u) & 0xFFFF0000u);
}

__global__ void sgcn_prep(const float* __restrict__ W, const float* __restrict__ A,
                          const float* __restrict__ b,
                          unsigned short* __restrict__ wbuf,
                          unsigned short* __restrict__ abuf,
                          float* __restrict__ b2buf) {
    int idx = blockIdx.x * 256 + threadIdx.x;
    if (idx < WBUF_ELEMS) {   // B-op: n=o, k=ci
        int j = idx & 7, lane = (idx >> 3) & 63, ks = (idx >> 9) & 1, nt = idx >> 10;
        int o  = nt * 16 + (lane & 15);
        int ci = ks * 32 + ((lane >> 4) & 3) * 8 + j;
        wbuf[idx] = bf16_rne(W[o * C_IN + ci]);
    }
    if (idx < ABUF_ELEMS) {   // B-op: n=w, k=v
        int j = idx & 7, lane = (idx >> 3) & 63, nt = (idx >> 9) & 1, k = idx >> 10;
        int w = nt * 16 + (lane & 15);
        int v = ((lane >> 4) & 3) * 8 + j;
        abuf[idx] = (v < V_DIM && w < V_DIM) ? bf16_rne(A[(k * V_DIM + v) * V_DIM + w])
                                             : (unsigned short)0;
    }
    if (idx < B2_ELEMS) {     // bias folded through stage-2
        int r = idx & 3, lane = (idx >> 2) & 63, nt = (idx >> 8) & 1, mt2 = idx >> 9;
        int c = mt2 * 16 + ((lane >> 4) & 3) * 4 + r;
        int w = nt * 16 + (lane & 15);
        float val = 0.f;
        if (w < V_DIM) {
            for (int k = 0; k < K_NUM; ++k) {
                float cs = 0.f;
                for (int v = 0; v < V_DIM; ++v) cs += A[(k * V_DIM + v) * V_DIM + w];
                val += b[k * C_OUT + c] * cs;
            }
        }
        b2buf[idx] = val;
    }
}

__global__ __launch_bounds__(512)
void sgcn_main(const float* __restrict__ x,
               const unsigned short* __restrict__ wbuf,
               const unsigned short* __restrict__ abuf,
               const float* __restrict__ b2buf,
               float* __restrict__ out) {
    __shared__ __align__(16) unsigned int   Xt[2][64 * 32];              // 2 x 8 KB
    __shared__ __align__(16) unsigned short H2[2][K_NUM * TT * 64 * 32]; // 2 x 24 KB

    const int tid  = threadIdx.x;
    const int lane = tid & 63;
    const int wid  = tid >> 6;
    const int nb   = blockIdx.x >> 6;
    const int t_base = (blockIdx.x & 63) * TWIN;

    const int wm2 = wid & 1;   // stage-1: col half (= t)
    const int wq  = wid >> 1;  // stage-1: o quarter
    const int mt2 = wid & 3, th = wid >> 2;   // stage-2: 4 c-tiles x 2 t

    // ---- hoisted loop-invariant fragments ----
    short8 wfr[3][2];
    #pragma unroll
    for (int ni = 0; ni < 3; ++ni)
        #pragma unroll
        for (int ks = 0; ks < 2; ++ks)
            wfr[ni][ks] = ((const short8*)wbuf)[(((wq * 3 + ni) * 2 + ks) * 64) + lane];
    short8 afr2[3][2];
    #pragma unroll
    for (int k = 0; k < 3; ++k)
        #pragma unroll
        for (int nt = 0; nt < 2; ++nt)
            afr2[k][nt] = ((const short8*)abuf)[((k * 2 + nt) * 64) + lane];
    floatx4 b2f[2];
    b2f[0] = reinterpret_cast<const floatx4*>(b2buf)[(mt2 * 2 + 0) * 64 + lane];
    b2f[1] = reinterpret_cast<const floatx4*>(b2buf)[(mt2 * 2 + 1) * 64 + lane];

    // zero never-written Xt pad cols (25..31, 57..63) in BOTH buffers
    for (int i = tid; i < 2 * 14 * 32; i += 512) {
        int bsel = i >= 14 * 32;
        int j = i - bsel * 14 * 32;
        int pc = j >> 5, ciw = j & 31;
        int col = (pc < 7) ? (25 + pc) : (50 + pc);
        Xt[bsel][col * 32 + ciw] = 0u;
    }

    // ---- x prefetch: one b128 item per thread (400 active) ----
    float xq[8];
    const float* xptr = x + ((size_t)nb * C_IN * T_DIM + t_base) * V_DIM;
    const int ciq = tid / 50, cg = tid % 50;       // item coords (tid<400)
    const int icol = (cg / 25) * 32 + (cg % 25);   // t*32 + v
    const int isw  = (ciq ^ ((icol >> 1) & 7)) * 4;

    auto LOADX = [&](int ts) {
        if (tid < 400) {
            const float* s = xptr + ts * (TT * V_DIM) + (size_t)(ciq * 8) * XROW + cg;
            #pragma unroll
            for (int r = 0; r < 8; ++r) xq[r] = s[(size_t)r * XROW];
        }
    };
    auto WRITEX = [&](int bsel) {
        if (tid < 400) {
            uintx4 pk;
            #pragma unroll
            for (int j = 0; j < 4; ++j)
                pk[j] = pack_rh(xq[2 * j], xq[2 * j + 1]);
            *reinterpret_cast<uintx4*>(&Xt[bsel][icol * 32 + isw]) = pk;
        }
    };

    LOADX(0);
    WRITEX(0);
    LOADX(1);

    #pragma unroll 1
    for (int ts = 0; ts <= NSUB; ++ts) {
        __syncthreads();   // the only barrier: fences Xt[cur] & H2[prv] producers
        const int cur = ts & 1, prv = 1 - cur;

        floatx4 acc1[2][3];
        short8 xfr[2][2];
        if (ts < NSUB) {
            // ---- stage-1 reads: H^T = Xt * W  (M=64 col, N=192 o, K=64) ----
            #pragma unroll
            for (int mi = 0; mi < 2; ++mi) {
                int acol = (wm2 * 2 + mi) * 16 + (lane & 15);
                #pragma unroll
                for (int ks = 0; ks < 2; ++ks) {
                    int blk = (ks * 4 + ((lane >> 4) & 3)) ^ ((acol >> 1) & 7);
                    xfr[mi][ks] = *(const short8*)&Xt[cur][acol * 32 + blk * 4];
                }
            }
        }

        // stage-2(ts-1) reads issued early (independent buffer)
        short8 ha[3];
        if (ts >= 1) {
            const int c_a = mt2 * 16 + (lane & 15);
            #pragma unroll
            for (int k = 0; k < K_NUM; ++k) {
                int row = (k * TT + th) * 64 + c_a;
                int blk = ((lane >> 4) & 3) ^ ((c_a >> 2) & 3);
                ha[k] = *(const short8*)&((const unsigned int*)H2[prv])[row * 16 + blk * 4];
            }
        }

        if (ts + 1 < NSUB) WRITEX(cur ^ 1);    // Xt[nxt]; disjoint from all reads
        if (ts + 2 < NSUB) LOADX(ts + 2);      // refill regs; hides under MFMA

        if (ts < NSUB) {
            #pragma unroll
            for (int mi = 0; mi < 2; ++mi)
                #pragma unroll
                for (int ni = 0; ni < 3; ++ni)
                    acc1[mi][ni] = floatx4{0.f, 0.f, 0.f, 0.f};
            #pragma unroll
            for (int mi = 0; mi < 2; ++mi)
                #pragma unroll
                for (int ni = 0; ni < 3; ++ni)
                    #pragma unroll
                    for (int ks = 0; ks < 2; ++ks)
                        acc1[mi][ni] = __builtin_amdgcn_mfma_f32_16x16x32_bf16(
                            xfr[mi][ks], wfr[ni][ks], acc1[mi][ni], 0, 0, 0);

            // H2[cur] write: 4 consecutive v per thread -> 2 pack_rh + 1 b64 write
            #pragma unroll
            for (int mi = 0; mi < 2; ++mi) {
                int vb = mi * 16 + ((lane >> 4) & 3) * 4;
                #pragma unroll
                for (int ni = 0; ni < 3; ++ni) {
                    int o = wq * 48 + ni * 16 + (lane & 15);
                    int k = o >> 6, c = o & 63;
                    int swv = vb ^ (((c >> 2) & 3) << 3);
                    unsigned long long lo = pack_rh(acc1[mi][ni][0], acc1[mi][ni][1]);
                    unsigned long long hi = pack_rh(acc1[mi][ni][2], acc1[mi][ni][3]);
                    int idx16 = ((k * TT + wm2) * 64 + c) * 32 + swv;
                    ((unsigned long long*)H2[cur])[idx16 >> 2] = lo | (hi << 32);
                }
            }
        }

        if (ts >= 1) {
            // ---- stage-2(ts-1): OUT[c][w] = sum_k H_k * A_k ----
            floatx4 acc2[2];
            acc2[0] = b2f[0];
            acc2[1] = b2f[1];
            #pragma unroll
            for (int k = 0; k < K_NUM; ++k)
                #pragma unroll
                for (int nt = 0; nt < 2; ++nt)
                    acc2[nt] = __builtin_amdgcn_mfma_f32_16x16x32_bf16(
                        ha[k], afr2[k][nt], acc2[nt], 0, 0, 0);

            const int tg = t_base + (ts - 1) * TT + th;
            const int c0 = mt2 * 16 + ((lane >> 4) & 3) * 4;
            const int wl = lane & 15;
            #pragma unroll
            for (int r = 0; r < 4; ++r)
                out[((size_t)(nb * C_OUT + c0 + r) * T_DIM + tg) * V_DIM + wl] = acc2[0][r];
            if (wl < 9) {
                #pragma unroll
                for (int r = 0; r < 4; ++r)
                    out[((size_t)(nb * C_OUT + c0 + r) * T_DIM + tg) * V_DIM + 16 + wl] = acc2[1][r];
            }
        }
    }
}

extern "C" void kernel_launch(void* const* d_in, const int* in_sizes, int n_in,
                              void* d_out, int out_size, void* d_ws, size_t ws_size,
                              hipStream_t stream) {
    const float* x = (const float*)d_in[0];
    const float* A = (const float*)d_in[1];
    const float* W = (const float*)d_in[2];
    const float* b = (const float*)d_in[3];
    float* out = (float*)d_out;

    unsigned short* wbuf = (unsigned short*)d_ws;
    unsigned short* abuf = (unsigned short*)((char*)d_ws + ABUF_OFF);
    float* b2buf = (float*)((char*)d_ws + B2_OFF);

    sgcn_prep<<<(WBUF_ELEMS + 255) / 256, 256, 0, stream>>>(W, A, b, wbuf, abuf, b2buf);

    dim3 grid(N_DIM * (T_DIM / TWIN));   // 1024 blocks x 512 threads
    sgcn_main<<<grid, 512, 0, stream>>>(x, wbuf, abuf, b2buf, out);
}